// Round 9
// baseline (703.185 us; speedup 1.0000x reference)
//
#include <hip/hip_runtime.h>
#include <hip/hip_fp16.h>

#define N_NODES  100000
#define N_EDGES  1200000
#define N_GRAPHS 1024
#define F        64
#define BN_EPS   1e-5f
#define NBUCK    ((N_NODES + 255) / 256)     // 391 buckets of 256 node IDs
#define NBLK     512                          // scatter blocks (chunks)
#define CHUNK    ((N_EDGES + NBLK - 1) / NBLK) // 2344 edges per chunk
#define MT       128                          // GEMM nodes per block
#define GS       32                           // graph slots per bucket
#define ASTRIDE  68                           // padded acc row (breaks bank aliasing)

// ---------------------------------------------------------------------------
// CSR-lite build: chist -> cscan -> bscan -> cscat   (place is GONE: the
// edge-parallel aggregator consumes `pairs` directly, no sorted eidx needed)
// ---------------------------------------------------------------------------
__global__ __launch_bounds__(256) void chist(const int* __restrict__ dst,
                                             int* __restrict__ Ct,
                                             int* __restrict__ hgbits) {
  __shared__ int lh[NBUCK];
  int b = blockIdx.x, t = threadIdx.x;
  int zidx = b * 256 + t;
  if (zidx < N_GRAPHS * F) hgbits[zidx] = 0;
  for (int i = t; i < NBUCK; i += 256) lh[i] = 0;
  __syncthreads();
  int e0 = b * CHUNK, e1 = e0 + CHUNK;
  if (e1 > N_EDGES) e1 = N_EDGES;
  for (int e = e0 + t; e < e1; e += 256) atomicAdd(&lh[dst[e] >> 8], 1);
  __syncthreads();
  for (int i = t; i < NBUCK; i += 256) Ct[(size_t)b * NBUCK + i] = lh[i];
}

__global__ __launch_bounds__(NBLK) void cscan(int* __restrict__ Ct,
                                              int* __restrict__ bcnt) {
  __shared__ int s[NBLK];
  int i = blockIdx.x, t = threadIdx.x;
  int v = Ct[(size_t)t * NBUCK + i];
  s[t] = v;
  __syncthreads();
  for (int off = 1; off < NBLK; off <<= 1) {
    int u = (t >= off) ? s[t - off] : 0;
    __syncthreads();
    s[t] += u;
    __syncthreads();
  }
  Ct[(size_t)t * NBUCK + i] = s[t] - v;
  if (t == NBLK - 1) bcnt[i] = s[NBLK - 1];
}

__global__ __launch_bounds__(512) void bscan(const int* __restrict__ bcnt,
                                             int* __restrict__ bstart) {
  __shared__ int s[512];
  int t = threadIdx.x;
  int v = (t < NBUCK) ? bcnt[t] : 0;
  s[t] = v;
  __syncthreads();
  for (int off = 1; off < 512; off <<= 1) {
    int u = (t >= off) ? s[t - off] : 0;
    __syncthreads();
    s[t] += u;
    __syncthreads();
  }
  if (t < NBUCK) bstart[t] = s[t] - v;
  if (t == 0) bstart[NBUCK] = N_EDGES;
}

__global__ __launch_bounds__(256) void cscat(const int* __restrict__ src,
                                             const int* __restrict__ dst,
                                             const int* __restrict__ Ct,
                                             const int* __restrict__ bstart,
                                             int* __restrict__ pairs) {
  __shared__ int cur[NBUCK];
  int b = blockIdx.x, t = threadIdx.x;
  for (int i = t; i < NBUCK; i += 256)
    cur[i] = bstart[i] + Ct[(size_t)b * NBUCK + i];
  __syncthreads();
  int e0 = b * CHUNK, e1 = e0 + CHUNK;
  if (e1 > N_EDGES) e1 = N_EDGES;
  for (int e = e0 + t; e < e1; e += 256) {
    int d = dst[e];
    int pos = atomicAdd(&cur[d >> 8], 1);
    pairs[pos] = (int)((((unsigned)d & 255u) << 24) | (unsigned)src[e]);
  }
}

// ---------------------------------------------------------------------------
// Dense GEMM: Uh[n] = feats[n] @ Wself, Zh[n] = feats[n] @ Wneigh (fp16 out).
// ---------------------------------------------------------------------------
__global__ __launch_bounds__(256) void gemm_uz(
    const float* __restrict__ feats, const float* __restrict__ Wself,
    const float* __restrict__ Wneigh, __half* __restrict__ Uh,
    __half* __restrict__ Zh) {
  __shared__ float As[MT * 65];
  __shared__ float Ws[64 * 128];
  int t = threadIdx.x;
  int mbase = blockIdx.x * MT;

  for (int i = t; i < 64 * 128; i += 256) {
    int k = i >> 7, j = i & 127;
    Ws[i] = (j < 64) ? Wself[k * 64 + j] : Wneigh[k * 64 + (j - 64)];
  }
#pragma unroll
  for (int s = 0; s < 8; s++) {
    int idx = (s * 256 + t) * 4;
    int m = idx >> 6, k = idx & 63;
    int gm = mbase + m;
    float4 v = (gm < N_NODES) ? *(const float4*)(feats + (size_t)gm * F + k)
                              : make_float4(0.f, 0.f, 0.f, 0.f);
    float* d = As + m * 65 + k;
    d[0] = v.x; d[1] = v.y; d[2] = v.z; d[3] = v.w;
  }
  __syncthreads();

  int wave = t >> 6, lane = t & 63;
  int jq = lane & 3, nq = lane >> 2;
  int half = wave & 1;
  int mb = (wave >> 1) * 64 + 4 * nq;
  int joff = half * 64 + jq * 16;

  float acc[4][16];
#pragma unroll
  for (int i = 0; i < 4; i++)
#pragma unroll
    for (int c = 0; c < 16; c++) acc[i][c] = 0.f;

#pragma unroll 4
  for (int k = 0; k < 64; k++) {
    float a0 = As[(mb + 0) * 65 + k];
    float a1 = As[(mb + 1) * 65 + k];
    float a2 = As[(mb + 2) * 65 + k];
    float a3 = As[(mb + 3) * 65 + k];
    const float4* wr = (const float4*)(Ws + k * 128 + joff);
    float4 w4[4];
    w4[0] = wr[0]; w4[1] = wr[1]; w4[2] = wr[2]; w4[3] = wr[3];
    const float* w = (const float*)w4;
#pragma unroll
    for (int c = 0; c < 16; c++) {
      float wv = w[c];
      acc[0][c] += a0 * wv;
      acc[1][c] += a1 * wv;
      acc[2][c] += a2 * wv;
      acc[3][c] += a3 * wv;
    }
  }

  __half* outp = half ? Zh : Uh;
  int jbase = jq * 16;
#pragma unroll
  for (int i = 0; i < 4; i++) {
    int gm = mbase + mb + i;
    if (gm < N_NODES) {
#pragma unroll
      for (int c4 = 0; c4 < 4; c4++) {
        union { __half h[4]; uint2 u; } pk;
        pk.h[0] = __float2half_rn(acc[i][c4 * 4 + 0]);
        pk.h[1] = __float2half_rn(acc[i][c4 * 4 + 1]);
        pk.h[2] = __float2half_rn(acc[i][c4 * 4 + 2]);
        pk.h[3] = __float2half_rn(acc[i][c4 * 4 + 3]);
        *(uint2*)(outp + (size_t)gm * F + jbase + c4 * 4) = pk.u;
      }
    }
  }
}

// ---------------------------------------------------------------------------
// Edge-parallel aggregate + SAGE update + ReLU + per-graph max. One block
// per bucket. Phase 1: independent edge iterations (broadcast pairs read +
// coalesced 128B Zh row + 4 LDS float atomicAdds + degree hist) -> deep
// memory pipeline, no dependent shfl->load chains. Phase 2: per-node
// h = relu(U + acc/deg + b), LDS atomicMax into per-graph slots. Phase 3:
// flush non-zero slots to hgbits (sorted gids -> ~3 graphs/bucket).
// ---------------------------------------------------------------------------
__global__ __launch_bounds__(256) void gather_agg(
    const __half* __restrict__ Uh, const __half* __restrict__ Zh,
    const int* __restrict__ pairs, const int* __restrict__ bstart,
    const float* __restrict__ bneigh, const int* __restrict__ gids,
    int* __restrict__ hgbits) {
  __shared__ float acc[256 * ASTRIDE];   // 69.6 KB
  __shared__ int   degh[256];
  __shared__ int   gmaxl[GS * 64];       // 8 KB (float bits; h>=0 so 0 = -inf)
  int b = blockIdx.x, t = threadIdx.x;
  int nb0 = b << 8;
  int nbkt = N_NODES - nb0; if (nbkt > 256) nbkt = 256;
  int r0 = bstart[b], r1 = bstart[b + 1];

  for (int i = t; i < 256 * ASTRIDE; i += 256) acc[i] = 0.f;
  degh[t] = 0;
  for (int i = t; i < GS * 64; i += 256) gmaxl[i] = 0;
  __syncthreads();

  int q  = t & 15;       // feature quad (4 floats)
  int eg = t >> 4;       // edge group 0..15

  for (int e = r0 + eg; e < r1; e += 16) {
    unsigned p = (unsigned)pairs[e];          // broadcast across 16 lanes
    int ld  = (int)(p >> 24);
    int sid = (int)(p & 0xFFFFFFu);
    uint2 z = *(const uint2*)(Zh + (size_t)sid * F + 4 * q);  // 128B/edge row
    float2 f0 = __half22float2(*(__half2*)&z.x);
    float2 f1 = __half22float2(*(__half2*)&z.y);
    float* a = acc + ld * ASTRIDE + 4 * q;
    atomicAdd(a + 0, f0.x);
    atomicAdd(a + 1, f0.y);
    atomicAdd(a + 2, f1.x);
    atomicAdd(a + 3, f1.y);
    if (q == 0) atomicAdd(&degh[ld], 1);
  }
  __syncthreads();

  float4 b4 = *(const float4*)(bneigh + 4 * q);
  int gid0 = gids[nb0];
#pragma unroll
  for (int pass = 0; pass < 16; pass++) {
    int nl = eg + pass * 16;
    if (nl < nbkt) {
      int node = nb0 + nl;
      float inv = 1.0f / fmaxf((float)degh[nl], 1.0f);
      uint2 u = *(const uint2*)(Uh + (size_t)node * F + 4 * q);
      float2 u0 = __half22float2(*(__half2*)&u.x);
      float2 u1 = __half22float2(*(__half2*)&u.y);
      const float* a = acc + nl * ASTRIDE + 4 * q;
      float hx = fmaxf(u0.x + a[0] * inv + b4.x, 0.f);
      float hy = fmaxf(u0.y + a[1] * inv + b4.y, 0.f);
      float hz = fmaxf(u1.x + a[2] * inv + b4.z, 0.f);
      float hw = fmaxf(u1.y + a[3] * inv + b4.w, 0.f);
      int slot = gids[node] - gid0;            // sorted -> small
      if (slot < GS) {
        int* gm = gmaxl + slot * 64 + 4 * q;
        atomicMax(gm + 0, __float_as_int(hx));
        atomicMax(gm + 1, __float_as_int(hy));
        atomicMax(gm + 2, __float_as_int(hz));
        atomicMax(gm + 3, __float_as_int(hw));
      } else {                                 // safety fallback
        int* hp = hgbits + (size_t)gids[node] * F + 4 * q;
        atomicMax(hp + 0, __float_as_int(hx));
        atomicMax(hp + 1, __float_as_int(hy));
        atomicMax(hp + 2, __float_as_int(hz));
        atomicMax(hp + 3, __float_as_int(hw));
      }
    }
  }
  __syncthreads();

  for (int i = t; i < GS * 64; i += 256) {
    int v = gmaxl[i];
    if (v != 0) {
      int slot = i >> 6, f = i & 63;
      atomicMax(&hgbits[(size_t)(gid0 + slot) * F + f], v);
    }
  }
}

// ---------------------------------------------------------------------------
// MLP head: weights staged in LDS once, 8 graphs per block.
// ---------------------------------------------------------------------------
#define GPB 8
__global__ __launch_bounds__(128) void mlp(
    const float* __restrict__ hg,
    const float* __restrict__ W1, const float* __restrict__ b1,
    const float* __restrict__ g1, const float* __restrict__ be1,
    const float* __restrict__ rm1, const float* __restrict__ rv1,
    const float* __restrict__ W2, const float* __restrict__ b2,
    const float* __restrict__ g2, const float* __restrict__ be2,
    const float* __restrict__ rm2, const float* __restrict__ rv2,
    const float* __restrict__ W3, const float* __restrict__ b3,
    float* __restrict__ out) {
  __shared__ float W1s[64 * 128];
  __shared__ float W2s[128 * 64];
  __shared__ float W3s[64];
  __shared__ float sc1[128], sh1[128], b1s[128];
  __shared__ float sc2[64],  sh2[64],  b2s[64];
  __shared__ float s0[64], s1[128], s2[64];
  int t = threadIdx.x;

  for (int i = t; i < 64 * 128; i += 128) W1s[i] = W1[i];
  for (int i = t; i < 128 * 64; i += 128) W2s[i] = W2[i];
  if (t < 64) W3s[t] = W3[t];
  {
    float iv = rsqrtf(rv1[t] + BN_EPS);
    float sc = g1[t] * iv;
    sc1[t] = sc; sh1[t] = be1[t] - rm1[t] * sc; b1s[t] = b1[t];
  }
  if (t < 64) {
    float iv = rsqrtf(rv2[t] + BN_EPS);
    float sc = g2[t] * iv;
    sc2[t] = sc; sh2[t] = be2[t] - rm2[t] * sc; b2s[t] = b2[t];
  }
  __syncthreads();

  for (int gg = 0; gg < GPB; gg++) {
    int g = blockIdx.x * GPB + gg;
    if (t < 64) s0[t] = hg[(size_t)g * F + t];
    __syncthreads();
    {
      float acc = b1s[t];
      for (int i = 0; i < 64; i++) acc += s0[i] * W1s[i * 128 + t];
      acc = fmaxf(acc, 0.0f);
      s1[t] = acc * sc1[t] + sh1[t];
    }
    __syncthreads();
    if (t < 64) {
      float acc = b2s[t];
      for (int i = 0; i < 128; i++) acc += s1[i] * W2s[i * 64 + t];
      acc = fmaxf(acc, 0.0f);
      s2[t] = acc * sc2[t] + sh2[t];
    }
    __syncthreads();
    if (t < 64) {
      float p = s2[t] * W3s[t];
      for (int off = 32; off > 0; off >>= 1) p += __shfl_down(p, off);
      if (t == 0) out[g] = p + b3[0];
    }
    __syncthreads();
  }
}

// ---------------------------------------------------------------------------
extern "C" void kernel_launch(void* const* d_in, const int* in_sizes, int n_in,
                              void* d_out, int out_size, void* d_ws, size_t ws_size,
                              hipStream_t stream) {
  const float* feats  = (const float*)d_in[0];
  const int*   src    = (const int*)d_in[1];
  const int*   dst    = (const int*)d_in[2];
  const int*   gids   = (const int*)d_in[3];
  const float* Wself  = (const float*)d_in[4];
  const float* Wneigh = (const float*)d_in[5];
  const float* bneigh = (const float*)d_in[6];
  const float* W1  = (const float*)d_in[7];
  const float* b1  = (const float*)d_in[8];
  const float* g1  = (const float*)d_in[9];
  const float* be1 = (const float*)d_in[10];
  const float* rm1 = (const float*)d_in[11];
  const float* rv1 = (const float*)d_in[12];
  const float* W2  = (const float*)d_in[13];
  const float* b2  = (const float*)d_in[14];
  const float* g2  = (const float*)d_in[15];
  const float* be2 = (const float*)d_in[16];
  const float* rm2 = (const float*)d_in[17];
  const float* rv2 = (const float*)d_in[18];
  const float* W3  = (const float*)d_in[19];
  const float* b3  = (const float*)d_in[20];

  // ws layout: Uh | Zh | bstart | bcnt | hgbits | Ct | pairs
  __half* Uh   = (__half*)d_ws;                      // N_NODES*64 halves
  __half* Zh   = Uh + (size_t)N_NODES * F;           // N_NODES*64 halves
  int* bstart  = (int*)(Zh + (size_t)N_NODES * F);   // NBUCK+1
  int* bcnt    = bstart + (NBUCK + 1);               // NBUCK
  int* hgbits  = bcnt + NBUCK;                       // N_GRAPHS*F (zeroed in chist)
  int* Ct      = hgbits + (size_t)N_GRAPHS * F;      // NBLK*NBUCK
  int* pairs   = Ct + (size_t)NBLK * NBUCK;          // N_EDGES

  chist<<<NBLK, 256, 0, stream>>>(dst, Ct, hgbits);
  cscan<<<NBUCK, NBLK, 0, stream>>>(Ct, bcnt);
  bscan<<<1, 512, 0, stream>>>(bcnt, bstart);
  cscat<<<NBLK, 256, 0, stream>>>(src, dst, Ct, bstart, pairs);
  gemm_uz<<<(N_NODES + MT - 1) / MT, 256, 0, stream>>>(feats, Wself, Wneigh,
                                                       Uh, Zh);
  gather_agg<<<NBUCK, 256, 0, stream>>>(Uh, Zh, pairs, bstart, bneigh,
                                        gids, hgbits);
  mlp<<<N_GRAPHS / GPB, 128, 0, stream>>>((const float*)hgbits,
                                          W1, b1, g1, be1, rm1, rv1,
                                          W2, b2, g2, be2, rm2, rv2, W3, b3,
                                          (float*)d_out);
}

// Round 10
// 243.406 us; speedup vs baseline: 2.8889x; 2.8889x over previous
//
#include <hip/hip_runtime.h>
#include <hip/hip_fp16.h>

#define N_NODES  100000
#define N_EDGES  1200000
#define N_GRAPHS 1024
#define F        64
#define BN_EPS   1e-5f
#define NBUCK    ((N_NODES + 255) / 256)     // 391 buckets of 256 node IDs
#define NBLK     512                          // scatter blocks (chunks)
#define CHUNK    ((N_EDGES + NBLK - 1) / NBLK) // 2344 edges per chunk
#define MT       128                          // GEMM nodes per block
#define GEMM_BLOCKS ((N_NODES + MT - 1) / MT)  // 782

// ---------------------------------------------------------------------------
// prep: fused [gemm_uz | chist] — independent work overlapped in one launch.
// Blocks [0, GEMM_BLOCKS) compute Uh/Zh; blocks [GEMM_BLOCKS, +NBLK) histogram
// dst buckets into Ct (and zero hgbits). LDS views share one 66KB arena.
// ---------------------------------------------------------------------------
__global__ __launch_bounds__(256) void prep(
    const float* __restrict__ feats, const float* __restrict__ Wself,
    const float* __restrict__ Wneigh, __half* __restrict__ Uh,
    __half* __restrict__ Zh, const int* __restrict__ dst,
    int* __restrict__ Ct, int* __restrict__ hgbits) {
  __shared__ __align__(16) char smraw[MT * 65 * 4 + 64 * 128 * 4];
  int t = threadIdx.x;

  if (blockIdx.x >= GEMM_BLOCKS) {
    // ---- chist part ----
    int* lh = (int*)smraw;
    int b = blockIdx.x - GEMM_BLOCKS;
    int zidx = b * 256 + t;
    if (zidx < N_GRAPHS * F) hgbits[zidx] = 0;
    for (int i = t; i < NBUCK; i += 256) lh[i] = 0;
    __syncthreads();
    int e0 = b * CHUNK, e1 = e0 + CHUNK;
    if (e1 > N_EDGES) e1 = N_EDGES;
    for (int e = e0 + t; e < e1; e += 256) atomicAdd(&lh[dst[e] >> 8], 1);
    __syncthreads();
    for (int i = t; i < NBUCK; i += 256) Ct[(size_t)b * NBUCK + i] = lh[i];
    return;
  }

  // ---- GEMM part: Uh = feats@Wself, Zh = feats@Wneigh (fp16 out) ----
  float* As = (float*)smraw;                   // MT x 65
  float* Ws = (float*)(smraw + MT * 65 * 4);   // 64 x 128
  int mbase = blockIdx.x * MT;

  for (int i = t; i < 64 * 128; i += 256) {
    int k = i >> 7, j = i & 127;
    Ws[i] = (j < 64) ? Wself[k * 64 + j] : Wneigh[k * 64 + (j - 64)];
  }
#pragma unroll
  for (int s = 0; s < 8; s++) {
    int idx = (s * 256 + t) * 4;
    int m = idx >> 6, k = idx & 63;
    int gm = mbase + m;
    float4 v = (gm < N_NODES) ? *(const float4*)(feats + (size_t)gm * F + k)
                              : make_float4(0.f, 0.f, 0.f, 0.f);
    float* d = As + m * 65 + k;
    d[0] = v.x; d[1] = v.y; d[2] = v.z; d[3] = v.w;
  }
  __syncthreads();

  int wave = t >> 6, lane = t & 63;
  int jq = lane & 3, nq = lane >> 2;
  int half = wave & 1;
  int mb = (wave >> 1) * 64 + 4 * nq;
  int joff = half * 64 + jq * 16;

  float acc[4][16];
#pragma unroll
  for (int i = 0; i < 4; i++)
#pragma unroll
    for (int c = 0; c < 16; c++) acc[i][c] = 0.f;

#pragma unroll 4
  for (int k = 0; k < 64; k++) {
    float a0 = As[(mb + 0) * 65 + k];
    float a1 = As[(mb + 1) * 65 + k];
    float a2 = As[(mb + 2) * 65 + k];
    float a3 = As[(mb + 3) * 65 + k];
    const float4* wr = (const float4*)(Ws + k * 128 + joff);
    float4 w4[4];
    w4[0] = wr[0]; w4[1] = wr[1]; w4[2] = wr[2]; w4[3] = wr[3];
    const float* w = (const float*)w4;
#pragma unroll
    for (int c = 0; c < 16; c++) {
      float wv = w[c];
      acc[0][c] += a0 * wv;
      acc[1][c] += a1 * wv;
      acc[2][c] += a2 * wv;
      acc[3][c] += a3 * wv;
    }
  }

  __half* outp = half ? Zh : Uh;
  int jbase = jq * 16;
#pragma unroll
  for (int i = 0; i < 4; i++) {
    int gm = mbase + mb + i;
    if (gm < N_NODES) {
#pragma unroll
      for (int c4 = 0; c4 < 4; c4++) {
        union { __half h[4]; uint2 u; } pk;
        pk.h[0] = __float2half_rn(acc[i][c4 * 4 + 0]);
        pk.h[1] = __float2half_rn(acc[i][c4 * 4 + 1]);
        pk.h[2] = __float2half_rn(acc[i][c4 * 4 + 2]);
        pk.h[3] = __float2half_rn(acc[i][c4 * 4 + 3]);
        *(uint2*)(outp + (size_t)gm * F + jbase + c4 * 4) = pk.u;
      }
    }
  }
}

// ---------------------------------------------------------------------------
// CSR build rest (proven): cscan -> bscan -> cscat -> place
// ---------------------------------------------------------------------------
__global__ __launch_bounds__(NBLK) void cscan(int* __restrict__ Ct,
                                              int* __restrict__ bcnt) {
  __shared__ int s[NBLK];
  int i = blockIdx.x, t = threadIdx.x;
  int v = Ct[(size_t)t * NBUCK + i];
  s[t] = v;
  __syncthreads();
  for (int off = 1; off < NBLK; off <<= 1) {
    int u = (t >= off) ? s[t - off] : 0;
    __syncthreads();
    s[t] += u;
    __syncthreads();
  }
  Ct[(size_t)t * NBUCK + i] = s[t] - v;
  if (t == NBLK - 1) bcnt[i] = s[NBLK - 1];
}

__global__ __launch_bounds__(512) void bscan(const int* __restrict__ bcnt,
                                             int* __restrict__ bstart) {
  __shared__ int s[512];
  int t = threadIdx.x;
  int v = (t < NBUCK) ? bcnt[t] : 0;
  s[t] = v;
  __syncthreads();
  for (int off = 1; off < 512; off <<= 1) {
    int u = (t >= off) ? s[t - off] : 0;
    __syncthreads();
    s[t] += u;
    __syncthreads();
  }
  if (t < NBUCK) bstart[t] = s[t] - v;
  if (t == 0) bstart[NBUCK] = N_EDGES;
}

__global__ __launch_bounds__(256) void cscat(const int* __restrict__ src,
                                             const int* __restrict__ dst,
                                             const int* __restrict__ Ct,
                                             const int* __restrict__ bstart,
                                             int* __restrict__ pairs) {
  __shared__ int cur[NBUCK];
  int b = blockIdx.x, t = threadIdx.x;
  for (int i = t; i < NBUCK; i += 256)
    cur[i] = bstart[i] + Ct[(size_t)b * NBUCK + i];
  __syncthreads();
  int e0 = b * CHUNK, e1 = e0 + CHUNK;
  if (e1 > N_EDGES) e1 = N_EDGES;
  for (int e = e0 + t; e < e1; e += 256) {
    int d = dst[e];
    int pos = atomicAdd(&cur[d >> 8], 1);
    pairs[pos] = (int)((((unsigned)d & 255u) << 24) | (unsigned)src[e]);
  }
}

__global__ __launch_bounds__(256) void place(const int* __restrict__ pairs,
                                             const int* __restrict__ bstart,
                                             int* __restrict__ rs,
                                             int* __restrict__ eidx) {
  __shared__ int lh[256];
  __shared__ int cur[256];
  int b = blockIdx.x, t = threadIdx.x;
  int nb0 = b << 8;
  int r0 = bstart[b], r1 = bstart[b + 1];

  lh[t] = 0;
  __syncthreads();
  for (int e = r0 + t; e < r1; e += 256)
    atomicAdd(&lh[((unsigned)pairs[e]) >> 24], 1);
  __syncthreads();

  int v = lh[t];
  cur[t] = v;
  __syncthreads();
  for (int off = 1; off < 256; off <<= 1) {
    int u = (t >= off) ? cur[t - off] : 0;
    __syncthreads();
    cur[t] += u;
    __syncthreads();
  }
  int excl = cur[t] - v;
  int node = nb0 + t;
  if (node < N_NODES) rs[node] = r0 + excl;
  if (b == 0 && t == 0) rs[N_NODES] = N_EDGES;
  __syncthreads();
  cur[t] = r0 + excl;
  __syncthreads();

  for (int e = r0 + t; e < r1; e += 256) {
    unsigned p = (unsigned)pairs[e];
    int pos = atomicAdd(&cur[p >> 24], 1);
    eidx[pos] = (int)(p & 0xFFFFFFu);
  }
}

// ---------------------------------------------------------------------------
// Fused gather + SAGE update + ReLU + per-graph max, v3: group-per-node.
// Each 16-lane group owns its own node (16 lanes x uint2 = full 128B Z-row),
// neighbor loop unrolled x4 -> 4 independent loads per group = 16 outstanding
// loads per wave (4x v2's MLP). No cross-sub reduction needed.
// ---------------------------------------------------------------------------
__global__ __launch_bounds__(256) void gather_h(
    const __half* __restrict__ Uh, const __half* __restrict__ Zh,
    const int* __restrict__ rs, const int* __restrict__ eidx,
    const float* __restrict__ bneigh, const int* __restrict__ gids,
    int* __restrict__ hgbits) {
  int lane = threadIdx.x & 63;
  int wid  = (blockIdx.x * blockDim.x + threadIdx.x) >> 6;
  const int NW = (2048 * 256) >> 6;                 // 8192 waves
  const int per = (N_NODES + NW - 1) / NW;          // 13 nodes/wave
  int n0 = wid * per;
  int n1 = n0 + per; if (n1 > N_NODES) n1 = N_NODES;
  int g  = lane >> 4;                               // group 0..3 (owns a node)
  int fl = lane & 15;                               // quad within the row
  int gl = g << 4;                                  // group's lane base
  float4 b4 = *(const float4*)(bneigh + 4 * fl);

  int curg = -1;
  float4 gmax = {0.f, 0.f, 0.f, 0.f};

  for (int n = n0 + g; n < n1; n += 4) {            // strided: balanced 4/3/3/3
    uint2 ur = *(const uint2*)(Uh + (size_t)n * F + 4 * fl);  // early U load
    int r0 = rs[n], r1 = rs[n + 1];                 // group-uniform
    float sx = 0.f, sy = 0.f, sz = 0.f, sw = 0.f;
    for (int base = r0; base < r1; base += 16) {
      int m = r1 - base; if (m > 16) m = 16;
      int myid = (fl < m) ? eidx[base + fl] : 0;
      for (int j = 0; j < m; j += 4) {
        int s0 = __shfl(myid, gl + j + 0);
        int s1 = __shfl(myid, gl + j + 1);
        int s2 = __shfl(myid, gl + j + 2);
        int s3 = __shfl(myid, gl + j + 3);
        uint2 z0 = *(const uint2*)(Zh + (size_t)s0 * F + 4 * fl);
        uint2 z1 = *(const uint2*)(Zh + (size_t)s1 * F + 4 * fl);
        uint2 z2 = *(const uint2*)(Zh + (size_t)s2 * F + 4 * fl);
        uint2 z3 = *(const uint2*)(Zh + (size_t)s3 * F + 4 * fl);
        {
          float2 f0 = __half22float2(*(__half2*)&z0.x);
          float2 f1 = __half22float2(*(__half2*)&z0.y);
          sx += f0.x; sy += f0.y; sz += f1.x; sw += f1.y;
        }
        if (j + 1 < m) {
          float2 f0 = __half22float2(*(__half2*)&z1.x);
          float2 f1 = __half22float2(*(__half2*)&z1.y);
          sx += f0.x; sy += f0.y; sz += f1.x; sw += f1.y;
        }
        if (j + 2 < m) {
          float2 f0 = __half22float2(*(__half2*)&z2.x);
          float2 f1 = __half22float2(*(__half2*)&z2.y);
          sx += f0.x; sy += f0.y; sz += f1.x; sw += f1.y;
        }
        if (j + 3 < m) {
          float2 f0 = __half22float2(*(__half2*)&z3.x);
          float2 f1 = __half22float2(*(__half2*)&z3.y);
          sx += f0.x; sy += f0.y; sz += f1.x; sw += f1.y;
        }
      }
    }
    float inv = 1.0f / fmaxf((float)(r1 - r0), 1.0f);
    float2 u0 = __half22float2(*(__half2*)&ur.x);
    float2 u1 = __half22float2(*(__half2*)&ur.y);
    float hx = fmaxf(u0.x + sx * inv + b4.x, 0.f);
    float hy = fmaxf(u0.y + sy * inv + b4.y, 0.f);
    float hz = fmaxf(u1.x + sz * inv + b4.z, 0.f);
    float hw = fmaxf(u1.y + sw * inv + b4.w, 0.f);

    int gg = gids[n];                               // group-uniform, ascending
    if (gg != curg) {
      if (curg >= 0) {
        int* hp = hgbits + (size_t)curg * F + 4 * fl;
        atomicMax(hp + 0, __float_as_int(gmax.x));
        atomicMax(hp + 1, __float_as_int(gmax.y));
        atomicMax(hp + 2, __float_as_int(gmax.z));
        atomicMax(hp + 3, __float_as_int(gmax.w));
      }
      curg = gg; gmax = make_float4(0.f, 0.f, 0.f, 0.f);
    }
    gmax.x = fmaxf(gmax.x, hx);
    gmax.y = fmaxf(gmax.y, hy);
    gmax.z = fmaxf(gmax.z, hz);
    gmax.w = fmaxf(gmax.w, hw);
  }
  if (curg >= 0) {
    int* hp = hgbits + (size_t)curg * F + 4 * fl;
    atomicMax(hp + 0, __float_as_int(gmax.x));
    atomicMax(hp + 1, __float_as_int(gmax.y));
    atomicMax(hp + 2, __float_as_int(gmax.z));
    atomicMax(hp + 3, __float_as_int(gmax.w));
  }
}

// ---------------------------------------------------------------------------
// MLP head: weights staged in LDS once, 8 graphs per block.
// ---------------------------------------------------------------------------
#define GPB 8
__global__ __launch_bounds__(128) void mlp(
    const float* __restrict__ hg,
    const float* __restrict__ W1, const float* __restrict__ b1,
    const float* __restrict__ g1, const float* __restrict__ be1,
    const float* __restrict__ rm1, const float* __restrict__ rv1,
    const float* __restrict__ W2, const float* __restrict__ b2,
    const float* __restrict__ g2, const float* __restrict__ be2,
    const float* __restrict__ rm2, const float* __restrict__ rv2,
    const float* __restrict__ W3, const float* __restrict__ b3,
    float* __restrict__ out) {
  __shared__ float W1s[64 * 128];
  __shared__ float W2s[128 * 64];
  __shared__ float W3s[64];
  __shared__ float sc1[128], sh1[128], b1s[128];
  __shared__ float sc2[64],  sh2[64],  b2s[64];
  __shared__ float s0[64], s1[128], s2[64];
  int t = threadIdx.x;

  for (int i = t; i < 64 * 128; i += 128) W1s[i] = W1[i];
  for (int i = t; i < 128 * 64; i += 128) W2s[i] = W2[i];
  if (t < 64) W3s[t] = W3[t];
  {
    float iv = rsqrtf(rv1[t] + BN_EPS);
    float sc = g1[t] * iv;
    sc1[t] = sc; sh1[t] = be1[t] - rm1[t] * sc; b1s[t] = b1[t];
  }
  if (t < 64) {
    float iv = rsqrtf(rv2[t] + BN_EPS);
    float sc = g2[t] * iv;
    sc2[t] = sc; sh2[t] = be2[t] - rm2[t] * sc; b2s[t] = b2[t];
  }
  __syncthreads();

  for (int gg = 0; gg < GPB; gg++) {
    int g = blockIdx.x * GPB + gg;
    if (t < 64) s0[t] = hg[(size_t)g * F + t];
    __syncthreads();
    {
      float acc = b1s[t];
      for (int i = 0; i < 64; i++) acc += s0[i] * W1s[i * 128 + t];
      acc = fmaxf(acc, 0.0f);
      s1[t] = acc * sc1[t] + sh1[t];
    }
    __syncthreads();
    if (t < 64) {
      float acc = b2s[t];
      for (int i = 0; i < 128; i++) acc += s1[i] * W2s[i * 64 + t];
      acc = fmaxf(acc, 0.0f);
      s2[t] = acc * sc2[t] + sh2[t];
    }
    __syncthreads();
    if (t < 64) {
      float p = s2[t] * W3s[t];
      for (int off = 32; off > 0; off >>= 1) p += __shfl_down(p, off);
      if (t == 0) out[g] = p + b3[0];
    }
    __syncthreads();
  }
}

// ---------------------------------------------------------------------------
extern "C" void kernel_launch(void* const* d_in, const int* in_sizes, int n_in,
                              void* d_out, int out_size, void* d_ws, size_t ws_size,
                              hipStream_t stream) {
  const float* feats  = (const float*)d_in[0];
  const int*   src    = (const int*)d_in[1];
  const int*   dst    = (const int*)d_in[2];
  const int*   gids   = (const int*)d_in[3];
  const float* Wself  = (const float*)d_in[4];
  const float* Wneigh = (const float*)d_in[5];
  const float* bneigh = (const float*)d_in[6];
  const float* W1  = (const float*)d_in[7];
  const float* b1  = (const float*)d_in[8];
  const float* g1  = (const float*)d_in[9];
  const float* be1 = (const float*)d_in[10];
  const float* rm1 = (const float*)d_in[11];
  const float* rv1 = (const float*)d_in[12];
  const float* W2  = (const float*)d_in[13];
  const float* b2  = (const float*)d_in[14];
  const float* g2  = (const float*)d_in[15];
  const float* be2 = (const float*)d_in[16];
  const float* rm2 = (const float*)d_in[17];
  const float* rv2 = (const float*)d_in[18];
  const float* W3  = (const float*)d_in[19];
  const float* b3  = (const float*)d_in[20];

  // ws layout: Uh | Zh | rs | bstart | bcnt | hgbits | Ct | pairs | eidx
  __half* Uh   = (__half*)d_ws;                      // N_NODES*64 halves
  __half* Zh   = Uh + (size_t)N_NODES * F;           // N_NODES*64 halves
  int* rs      = (int*)(Zh + (size_t)N_NODES * F);   // N_NODES+1
  int* bstart  = rs + (N_NODES + 1);                 // NBUCK+1
  int* bcnt    = bstart + (NBUCK + 1);               // NBUCK
  int* hgbits  = bcnt + NBUCK;                       // N_GRAPHS*F (zeroed in prep)
  int* Ct      = hgbits + (size_t)N_GRAPHS * F;      // NBLK*NBUCK
  int* pairs   = Ct + (size_t)NBLK * NBUCK;          // N_EDGES
  int* eidx    = pairs + N_EDGES;                    // N_EDGES

  prep<<<GEMM_BLOCKS + NBLK, 256, 0, stream>>>(feats, Wself, Wneigh, Uh, Zh,
                                               dst, Ct, hgbits);
  cscan<<<NBUCK, NBLK, 0, stream>>>(Ct, bcnt);
  bscan<<<1, 512, 0, stream>>>(bcnt, bstart);
  cscat<<<NBLK, 256, 0, stream>>>(src, dst, Ct, bstart, pairs);
  place<<<NBUCK, 256, 0, stream>>>(pairs, bstart, rs, eidx);
  gather_h<<<2048, 256, 0, stream>>>(Uh, Zh, rs, eidx, bneigh, gids, hgbits);
  mlp<<<N_GRAPHS / GPB, 128, 0, stream>>>((const float*)hgbits,
                                          W1, b1, g1, be1, rm1, rv1,
                                          W2, b2, g2, be2, rm2, rv2, W3, b3,
                                          (float*)d_out);
}